// Round 2
// baseline (232.075 us; speedup 1.0000x reference)
//
#include <hip/hip_runtime.h>
#include <hip/hip_bf16.h>
#include <stdint.h>

// Problem constants (fixed by the reference)
#define NTOK 4096
#define HID  512
#define INSZ 1024   // E + H
#define KIN  1536   // INSZ + HID (fused LSTM input: x | h)
#define KCAT 64
#define CCH  128
#define MCELL 4
#define G4H  2048   // 4*H
#define SLOTS 4608  // ci slot space (4 buckets padded to 128)

typedef unsigned short u16;
typedef __bf16 bf16x8 __attribute__((ext_vector_type(8)));
typedef float  f32x4  __attribute__((ext_vector_type(4)));

__device__ __forceinline__ u16 f2bf(float f) {
    unsigned u = __float_as_uint(f);
    u += 0x7fffu + ((u >> 16) & 1u);   // RTNE
    return (u16)(u >> 16);
}
__device__ __forceinline__ float bf2f(u16 v) {
    return __uint_as_float(((unsigned)v) << 16);
}
__device__ __forceinline__ void store_bf8(u16* p, float4 a, float4 b) {
    ushort4 r0, r1;
    r0.x = f2bf(a.x); r0.y = f2bf(a.y); r0.z = f2bf(a.z); r0.w = f2bf(a.w);
    r1.x = f2bf(b.x); r1.y = f2bf(b.y); r1.z = f2bf(b.z); r1.w = f2bf(b.w);
    *reinterpret_cast<ushort4*>(p) = r0;
    *reinterpret_cast<ushort4*>(p + 4) = r1;
}
__device__ __forceinline__ void gl16(const u16* g, u16* l) {
    __builtin_amdgcn_global_load_lds((const __attribute__((address_space(1))) void*)g,
                                     (__attribute__((address_space(3))) void*)l, 16, 0, 0);
}

// meta layout (ints): [0..3] ci padded cnt, [4..7] ci padded off,
// [8..71] cat padded cnt, [72..135] cat padded off, [136..263] tile->cat LUT
// ---------------------------------------------------------------------------
// Dispatch 0: fat_pack — block 0 builds perms (ci pad 128, cat pad 64);
// blocks 1..2047 pack weights (Wb gate-INTERLEAVED: packed col j holds source
// gate-row (j&3)*512 + (j>>2)) and A_tok (token order, row 4096 = zeros).
// ---------------------------------------------------------------------------
#define CH_W  (8192 * 192)
#define CH_L  (8192 * 64)
#define CH_A  (4097 * 192)
#define CH_TOT (CH_W + CH_L + CH_A)
#define PK_BLOCKS 2048

__global__ __launch_bounds__(256) void fat_pack(
    const float* __restrict__ x, const float* __restrict__ h,
    const float* __restrict__ Wih, const float* __restrict__ Whh,
    const float* __restrict__ W_lin,
    const int* __restrict__ ci, const int* __restrict__ cat,
    int* __restrict__ meta, int* __restrict__ perm_ci, int* __restrict__ perm_cat,
    u16* __restrict__ A_tok, u16* __restrict__ Wb, u16* __restrict__ Wlin)
{
    if (blockIdx.x == 0) {
        __shared__ int cnt_ci[MCELL], cur_ci[MCELL];
        __shared__ int cnt_cat[KCAT], cur_cat[KCAT];
        int tid = threadIdx.x;
        if (tid < MCELL) cnt_ci[tid] = 0;
        if (tid < KCAT)  cnt_cat[tid] = 0;
        __syncthreads();
        for (int t = tid; t < NTOK; t += 256) {
            atomicAdd(&cnt_ci[ci[t]], 1);
            atomicAdd(&cnt_cat[cat[t]], 1);
        }
        __syncthreads();
        if (tid == 0) {
            int off = 0;
            for (int m = 0; m < MCELL; ++m) {
                int p = (cnt_ci[m] + 127) & ~127;
                meta[m] = p; meta[4 + m] = off; cur_ci[m] = off; off += p;
            }
            off = 0;
            for (int i = 0; i < 128; ++i) meta[136 + i] = -1;
            for (int k = 0; k < KCAT; ++k) {
                int p = (cnt_cat[k] + 63) & ~63;
                meta[8 + k] = p; meta[72 + k] = off; cur_cat[k] = off;
                for (int i = 0; i < p / 64; ++i) meta[136 + off / 64 + i] = k;
                off += p;
            }
        }
        __syncthreads();
        for (int i = tid; i < SLOTS; i += 256) perm_ci[i] = -1;
        for (int i = tid; i < 8192; i += 256) perm_cat[i] = -1;
        __syncthreads();
        for (int t = tid; t < NTOK; t += 256) {
            perm_ci[atomicAdd(&cur_ci[ci[t]], 1)] = t;
            perm_cat[atomicAdd(&cur_cat[cat[t]], 1)] = t;
        }
        return;
    }
    for (int i = (blockIdx.x - 1) * 256 + threadIdx.x; i < CH_TOT; i += (PK_BLOCKS - 1) * 256) {
        if (i < CH_W) {
            int row = i / 192, cc = i - row * 192;
            int m = row >> 11, j = row & 2047;
            int srow = (j & 3) * HID + (j >> 2);   // gate-interleave
            int c = cc * 8;
            const float* src = (c < INSZ) ? (Wih + ((size_t)m * G4H + srow) * INSZ + c)
                                          : (Whh + ((size_t)m * G4H + srow) * HID + (c - INSZ));
            store_bf8(Wb + (size_t)row * KIN + c,
                      *(const float4*)src, *(const float4*)(src + 4));
        } else if (i < CH_W + CH_L) {
            int i2 = i - CH_W;
            int row = i2 >> 6, cc = i2 & 63;
            const float* src = W_lin + (size_t)row * HID + cc * 8;
            store_bf8(Wlin + (size_t)row * HID + cc * 8,
                      *(const float4*)src, *(const float4*)(src + 4));
        } else {
            int i3 = i - (CH_W + CH_L);
            int row = i3 / 192, cc = i3 - row * 192;
            int c = cc * 8;
            u16* dst = A_tok + (size_t)row * KIN + c;
            if (row == NTOK) {
                *reinterpret_cast<int4*>(dst) = make_int4(0, 0, 0, 0);
            } else {
                const float* src = (c < INSZ) ? (x + (size_t)row * INSZ + c)
                                              : (h + (size_t)row * HID + (c - INSZ));
                store_bf8(dst, *(const float4*)src, *(const float4*)(src + 4));
            }
        }
    }
}

// ---------------------------------------------------------------------------
// Dispatch 1: fused GEMMs + LSTM epilogue.
//  gates ids [0,2048): 128x128 tile, K-FULL (1536), 4 waves of 64x64 (4x4
//    frags). Double-buffered LDS (4x16KB), counted s_waitcnt vmcnt(8) so each
//    buffer's 8 global_load_lds have a full K-step in flight (T3/T4 minimum).
//    Raw s_barrier (no vmcnt(0) drain in main loop); sched_barrier(0) pins
//    phase boundaries. Wb gate-interleaved -> fused in-register LSTM epilogue
//    (4x4 shfl_xor transpose), unchanged from R1.
//  logodds ids [2048,2176): 64x128 tiles, K=512 (unchanged).
// LDS chunk-XOR swizzle unchanged (0-conflict proven).
// ---------------------------------------------------------------------------
#define FENCE() __builtin_amdgcn_sched_barrier(0)

__global__ __launch_bounds__(256, 2) void mega_gemm(
    const u16* __restrict__ A_tok,    // [4097][1536] token order bf16
    const u16* __restrict__ Wb,       // [4][2048][1536] gate-interleaved
    const u16* __restrict__ Wlin,     // [64][128][512]
    const float* __restrict__ et,     // [4096][512] f32
    const float* __restrict__ b_lin,  // [64,128]
    const float* __restrict__ c,      // [4096][512]
    const float* __restrict__ b_ih,   // [4,2048]
    const float* __restrict__ b_hh,   // [4,2048]
    const int* __restrict__ meta,
    const int* __restrict__ perm_ci,
    const int* __restrict__ perm_cat,
    float* __restrict__ out)
{
    // 64 KB: gates dbuf A0[0,8192) A1[8192,16384) B0[16384,24576) B1[24576,32768)
    // log_odds reuses [0,8192) for W staging and [8192,12288) for et staging.
    __shared__ __align__(16) u16 S[32768];
    __shared__ int sperm[128];

    int tid = threadIdx.x;
    int lane = tid & 63, wave = tid >> 6;
    int qd = lane >> 4, l15 = lane & 15;
    int rsw = l15 & 7;

    int id = blockIdx.x;
    if (id < 2048) {
        // ---------------- gates GEMM, K-full, pipelined ----------------
        int g = id & 63;                      // (m,ct) group -> fixes XCD
        int rt = id >> 6;                     // 0..31 row tile
        int m = g >> 4, ct = g & 15;
        int pcnt = meta[m];
        if (rt * 128 >= pcnt) return;
        int row0 = meta[4 + m] + rt * 128;

        if (tid < 128) sperm[tid] = perm_ci[row0 + tid];
        __syncthreads();

        // per thread: 4 A chunks + 4 B chunks per K-step (q = j*256 + tid)
        const u16* gA[4]; const u16* gB[4];
        int qq[4];
        #pragma unroll
        for (int j = 0; j < 4; ++j) {
            int q = j * 256 + tid;
            int row = q >> 3, kc = (q & 7) ^ (row & 7);
            int t = sperm[row];
            gA[j] = A_tok + (size_t)(t >= 0 ? t : NTOK) * KIN + kc * 8;
            gB[j] = Wb + ((size_t)m * G4H + ct * 128 + row) * KIN + kc * 8;
            qq[j] = q * 8;
        }

        int wm = wave >> 1, wn = wave & 1;    // wave tile: rows wm*64, cols wn*64

        f32x4 acc[4][4];
        #pragma unroll
        for (int i = 0; i < 4; ++i)
            #pragma unroll
            for (int j = 0; j < 4; ++j)
                acc[i][j] = (f32x4){0.f, 0.f, 0.f, 0.f};

#define STAGE(ABASE, BBASE) do { \
        _Pragma("unroll") \
        for (int j = 0; j < 4; ++j) { gl16(gA[j], &S[(ABASE) + qq[j]]); gA[j] += 64; } \
        _Pragma("unroll") \
        for (int j = 0; j < 4; ++j) { gl16(gB[j], &S[(BBASE) + qq[j]]); gB[j] += 64; } \
    } while (0)

#define GEMM_STEP(ABASE, BBASE) do { \
        _Pragma("unroll") \
        for (int ks2 = 0; ks2 < 2; ++ks2) { \
            int ch = (ks2 * 4 + qd) ^ rsw; \
            bf16x8 fb[4]; \
            _Pragma("unroll") \
            for (int tj = 0; tj < 4; ++tj) \
                fb[tj] = *reinterpret_cast<const bf16x8*>(&S[(BBASE) + (wn * 64 + tj * 16 + l15) * 64 + ch * 8]); \
            _Pragma("unroll") \
            for (int ti = 0; ti < 4; ++ti) { \
                bf16x8 fa = *reinterpret_cast<const bf16x8*>(&S[(ABASE) + (wm * 64 + ti * 16 + l15) * 64 + ch * 8]); \
                _Pragma("unroll") \
                for (int tj = 0; tj < 4; ++tj) \
                    acc[ti][tj] = __builtin_amdgcn_mfma_f32_16x16x32_bf16(fa, fb[tj], acc[ti][tj], 0, 0, 0); \
            } \
        } \
    } while (0)

        STAGE(0, 16384);                      // prologue: buf0 <- step 0
        for (int ks = 0; ks < 24; ks += 2) {
            STAGE(8192, 24576);               // buf1 <- step ks+1
            asm volatile("s_waitcnt vmcnt(8)" ::: "memory");  // buf0 ready
            FENCE();
            __builtin_amdgcn_s_barrier();
            FENCE();
            GEMM_STEP(0, 16384);
            FENCE();
            __builtin_amdgcn_s_barrier();     // all reads of buf0 done
            FENCE();
            if (ks + 2 < 24) {
                STAGE(0, 16384);              // buf0 <- step ks+2
                asm volatile("s_waitcnt vmcnt(8)" ::: "memory");  // buf1 ready
            } else {
                asm volatile("s_waitcnt vmcnt(0)" ::: "memory");
            }
            FENCE();
            __builtin_amdgcn_s_barrier();
            FENCE();
            GEMM_STEP(8192, 24576);
            FENCE();
            __builtin_amdgcn_s_barrier();     // all reads of buf1 done
            FENCE();
        }
#undef STAGE
#undef GEMM_STEP

        // -------- fused LSTM epilogue (unchanged math from R1) --------
        // packed col = ct*128 + wn*64 + tj*16 + l15 ; gate gt = l15&3,
        // unit u = ct*32 + wn*16 + tj*4 + (l15>>2). 4-lane group holds the 4
        // gates of one u over rows qd*4+rr; 4x4 shfl_xor transpose -> lane
        // (lane&3) ends with i,f,g,o of row rr = lane&3.
        int gt = l15 & 3;
        float bias[4];
        #pragma unroll
        for (int tj = 0; tj < 4; ++tj) {
            int u = ct * 32 + wn * 16 + tj * 4 + (l15 >> 2);
            bias[tj] = b_ih[m * G4H + gt * HID + u] + b_hh[m * G4H + gt * HID + u];
        }
        int b0 = lane & 1, b1 = lane & 2;
        const size_t o_h2 = (size_t)NTOK * CCH;
        const size_t o_c2 = o_h2 + (size_t)NTOK * HID;
        #pragma unroll
        for (int ti = 0; ti < 4; ++ti) {
            int t = sperm[wm * 64 + ti * 16 + qd * 4 + (lane & 3)];
            #pragma unroll
            for (int tj = 0; tj < 4; ++tj) {
                float v0 = acc[ti][tj][0] + bias[tj];
                float v1 = acc[ti][tj][1] + bias[tj];
                float v2 = acc[ti][tj][2] + bias[tj];
                float v3 = acc[ti][tj][3] + bias[tj];
                float tmp;
                tmp = __shfl_xor(b0 ? v0 : v1, 1); if (b0) v0 = tmp; else v1 = tmp;
                tmp = __shfl_xor(b0 ? v2 : v3, 1); if (b0) v2 = tmp; else v3 = tmp;
                tmp = __shfl_xor(b1 ? v0 : v2, 2); if (b1) v0 = tmp; else v2 = tmp;
                tmp = __shfl_xor(b1 ? v1 : v3, 2); if (b1) v1 = tmp; else v3 = tmp;
                if (t >= 0) {
                    int u = ct * 32 + wn * 16 + tj * 4 + (l15 >> 2);
                    float si = 1.f / (1.f + __expf(-v0));
                    float sf = 1.f / (1.f + __expf(-v1));
                    float tg = tanhf(v2);
                    float so = 1.f / (1.f + __expf(-v3));
                    float cold = c[(size_t)t * HID + u];
                    float c2 = sf * cold + si * tg;
                    float h2 = so * tanhf(c2);
                    out[o_h2 + (size_t)t * HID + u] = h2;
                    out[o_c2 + (size_t)t * HID + u] = c2;
                }
            }
        }
    } else {
        // ---------------- log_odds GEMM (64 x 128, K=512) ----------------
        u16* As = S;                          // 8192 u16
        u16* Bs = S + 8192;                   // 4096 u16
        int rtl = id - 2048;                  // 0..127 global slot tile
        int k = meta[136 + rtl];
        if (k < 0) return;
        int r0 = rtl * 64;

        if (tid < 64) sperm[tid] = perm_cat[r0 + tid];
        __syncthreads();

        int rb = tid >> 3;                    // 0..31
        int kc = (tid & 7) ^ (rb & 7);

        // B = Wlin[k] (128 x 64/iter) via gl16 into As
        const u16* gW[4]; u16* lW[4];
        #pragma unroll
        for (int i = 0; i < 4; ++i) {
            gW[i] = Wlin + ((size_t)k * CCH + i * 32 + rb) * HID + kc * 8;
            lW[i] = As + (i * 256 + wave * 64) * 8;
        }
        // A = et rows gathered, f32->bf16 VALU staging into Bs (64 x 64/iter)
        int ar = tid >> 2;                    // 0..63
        int acp = tid & 3;                    // 2 chunks each
        int at = sperm[ar];
        const float* asrc = (at >= 0) ? (et + (size_t)at * HID) : nullptr;

        f32x4 acc[4][2];
        #pragma unroll
        for (int i = 0; i < 4; ++i) {
            acc[i][0] = (f32x4){0.f, 0.f, 0.f, 0.f};
            acc[i][1] = (f32x4){0.f, 0.f, 0.f, 0.f};
        }

        for (int kk = 0; kk < HID; kk += 64) {
            #pragma unroll
            for (int i = 0; i < 4; ++i) { gl16(gW[i], lW[i]); gW[i] += 64; }
            #pragma unroll
            for (int j = 0; j < 2; ++j) {
                int dch = acp * 2 + j;
                int sch = dch ^ (ar & 7);
                u16* dst = &Bs[ar * 64 + dch * 8];
                if (asrc) {
                    const float* s = asrc + kk + sch * 8;
                    store_bf8(dst, *(const float4*)s, *(const float4*)(s + 4));
                } else {
                    *reinterpret_cast<int4*>(dst) = make_int4(0, 0, 0, 0);
                }
            }
            __syncthreads();
            #pragma unroll
            for (int ks2 = 0; ks2 < 2; ++ks2) {
                int ch = (ks2 * 4 + qd) ^ rsw;
                bf16x8 fa[4], fb[2];
                #pragma unroll
                for (int ti = 0; ti < 4; ++ti)
                    fa[ti] = *reinterpret_cast<const bf16x8*>(&Bs[(ti * 16 + l15) * 64 + ch * 8]);
                #pragma unroll
                for (int tj = 0; tj < 2; ++tj)
                    fb[tj] = *reinterpret_cast<const bf16x8*>(&As[(wave * 32 + tj * 16 + l15) * 64 + ch * 8]);
                #pragma unroll
                for (int ti = 0; ti < 4; ++ti)
                    #pragma unroll
                    for (int tj = 0; tj < 2; ++tj)
                        acc[ti][tj] = __builtin_amdgcn_mfma_f32_16x16x32_bf16(fa[ti], fb[tj], acc[ti][tj], 0, 0, 0);
            }
            __syncthreads();
        }

        #pragma unroll
        for (int ti = 0; ti < 4; ++ti) {
            #pragma unroll
            for (int tj = 0; tj < 2; ++tj) {
                int n = wave * 32 + tj * 16 + l15;
                float bias = b_lin[k * CCH + n];
                #pragma unroll
                for (int rr = 0; rr < 4; ++rr) {
                    int row = ti * 16 + qd * 4 + rr;
                    int t = sperm[row];
                    if (t >= 0)
                        out[(size_t)t * CCH + n] = acc[ti][tj][rr] + bias;
                }
            }
        }
    }
}

// ---------------------------------------------------------------------------
extern "C" void kernel_launch(void* const* d_in, const int* in_sizes, int n_in,
                              void* d_out, int out_size, void* d_ws, size_t ws_size,
                              hipStream_t stream) {
    const float* et    = (const float*)d_in[0];
    const float* x     = (const float*)d_in[1];
    const float* h     = (const float*)d_in[2];
    const float* c     = (const float*)d_in[3];
    const int*   cat   = (const int*)d_in[4];
    const int*   ci    = (const int*)d_in[5];
    const float* W_lin = (const float*)d_in[6];
    const float* b_lin = (const float*)d_in[7];
    const float* W_ih  = (const float*)d_in[8];
    const float* W_hh  = (const float*)d_in[9];
    const float* b_ih  = (const float*)d_in[10];
    const float* b_hh  = (const float*)d_in[11];
    float* out = (float*)d_out;

    char* ws = (char*)d_ws;
    int* meta     = (int*)ws;                         // 264 ints used (2 KB resv)
    int* perm_ci  = (int*)(ws + 2048);                // 4608 ints (20 KB resv)
    int* perm_cat = (int*)(ws + 22528);               // 8192 ints -> 55296
    u16* A_tok    = (u16*)(ws + 55296);               // 4097*1536*2 -> 12641280
    u16* Wb       = (u16*)(ws + 12641280);            // 8192*1536*2 -> 37807104
    u16* Wlin     = (u16*)(ws + 37807104);            // 8192*512*2  -> 46195712

    fat_pack<<<PK_BLOCKS, 256, 0, stream>>>(x, h, W_ih, W_hh, W_lin, ci, cat,
                                            meta, perm_ci, perm_cat, A_tok, Wb, Wlin);

    mega_gemm<<<2048 + 128, 256, 0, stream>>>(A_tok, Wb, Wlin, et, b_lin, c,
                                              b_ih, b_hh, meta, perm_ci, perm_cat, out);
}

// Round 3
// 220.713 us; speedup vs baseline: 1.0515x; 1.0515x over previous
//
#include <hip/hip_runtime.h>
#include <hip/hip_bf16.h>
#include <stdint.h>

// Problem constants (fixed by the reference)
#define NTOK 4096
#define HID  512
#define INSZ 1024   // E + H
#define KIN  1536   // INSZ + HID (fused LSTM input: x | h)
#define KCAT 64
#define CCH  128
#define MCELL 4
#define G4H  2048   // 4*H
#define SLOTS 4992  // ci slot space (4 buckets padded to 192; worst < 4096+4*192)

typedef unsigned short u16;
typedef __bf16 bf16x8 __attribute__((ext_vector_type(8)));
typedef float  f32x4  __attribute__((ext_vector_type(4)));

__device__ __forceinline__ u16 f2bf(float f) {
    unsigned u = __float_as_uint(f);
    u += 0x7fffu + ((u >> 16) & 1u);   // RTNE
    return (u16)(u >> 16);
}
__device__ __forceinline__ float bf2f(u16 v) {
    return __uint_as_float(((unsigned)v) << 16);
}
__device__ __forceinline__ void store_bf8(u16* p, float4 a, float4 b) {
    ushort4 r0, r1;
    r0.x = f2bf(a.x); r0.y = f2bf(a.y); r0.z = f2bf(a.z); r0.w = f2bf(a.w);
    r1.x = f2bf(b.x); r1.y = f2bf(b.y); r1.z = f2bf(b.z); r1.w = f2bf(b.w);
    *reinterpret_cast<ushort4*>(p) = r0;
    *reinterpret_cast<ushort4*>(p + 4) = r1;
}
__device__ __forceinline__ void gl16(const u16* g, u16* l) {
    __builtin_amdgcn_global_load_lds((const __attribute__((address_space(1))) void*)g,
                                     (__attribute__((address_space(3))) void*)l, 16, 0, 0);
}

// meta layout (ints): [0..3] ci padded cnt, [4..7] ci padded off,
// [8..71] cat padded cnt, [72..135] cat padded off, [136..263] tile->cat LUT
// ---------------------------------------------------------------------------
// Dispatch 0: fat_pack — block 0 builds perms with a FULLY PARALLEL meta
// build (64-wide LDS scan; no serial tid==0 global-write chain). ci buckets
// pad to 192, cat buckets pad to 64. Blocks 1..2047 pack weights (Wb
// gate-INTERLEAVED: packed col j holds source gate-row (j&3)*512 + (j>>2))
// and A_tok (token order, row 4096 = zeros).
// ---------------------------------------------------------------------------
#define CH_W  (8192 * 192)
#define CH_L  (8192 * 64)
#define CH_A  (4097 * 192)
#define CH_TOT (CH_W + CH_L + CH_A)
#define PK_BLOCKS 2048

__global__ __launch_bounds__(256) void fat_pack(
    const float* __restrict__ x, const float* __restrict__ h,
    const float* __restrict__ Wih, const float* __restrict__ Whh,
    const float* __restrict__ W_lin,
    const int* __restrict__ ci, const int* __restrict__ cat,
    int* __restrict__ meta, int* __restrict__ perm_ci, int* __restrict__ perm_cat,
    u16* __restrict__ A_tok, u16* __restrict__ Wb, u16* __restrict__ Wlin)
{
    if (blockIdx.x == 0) {
        __shared__ int cnt_ci[MCELL], cur_ci[MCELL];
        __shared__ int cnt_cat[KCAT], cur_cat[KCAT];
        __shared__ int scan_cat[KCAT];
        int tid = threadIdx.x;
        if (tid < MCELL) cnt_ci[tid] = 0;
        if (tid < KCAT)  cnt_cat[tid] = 0;
        __syncthreads();
        for (int t = tid; t < NTOK; t += 256) {
            atomicAdd(&cnt_ci[ci[t]], 1);
            atomicAdd(&cnt_cat[cat[t]], 1);
        }
        __syncthreads();
        // parallel meta build
        for (int i = tid; i < 128; i += 256) meta[136 + i] = -1;   // LUT default
        if (tid < MCELL) {
            int off = 0;
            for (int i = 0; i < tid; ++i) off += (cnt_ci[i] + 191) / 192 * 192;
            int p = (cnt_ci[tid] + 191) / 192 * 192;
            meta[tid] = p; meta[4 + tid] = off; cur_ci[tid] = off;
        }
        if (tid < KCAT) scan_cat[tid] = (cnt_cat[tid] + 63) & ~63;
        __syncthreads();
        for (int d = 1; d < KCAT; d <<= 1) {        // Hillis-Steele inclusive
            int v = 0;
            if (tid < KCAT && tid >= d) v = scan_cat[tid - d];
            __syncthreads();
            if (tid < KCAT) scan_cat[tid] += v;
            __syncthreads();
        }
        if (tid < KCAT) {
            int p = (cnt_cat[tid] + 63) & ~63;
            int off = scan_cat[tid] - p;            // exclusive
            meta[8 + tid] = p; meta[72 + tid] = off; cur_cat[tid] = off;
            for (int i = 0; i < p / 64; ++i) meta[136 + off / 64 + i] = tid;
        }
        __syncthreads();
        for (int i = tid; i < SLOTS; i += 256) perm_ci[i] = -1;
        for (int i = tid; i < 8192; i += 256) perm_cat[i] = -1;
        __syncthreads();
        for (int t = tid; t < NTOK; t += 256) {
            perm_ci[atomicAdd(&cur_ci[ci[t]], 1)] = t;
            perm_cat[atomicAdd(&cur_cat[cat[t]], 1)] = t;
        }
        return;
    }
    for (int i = (blockIdx.x - 1) * 256 + threadIdx.x; i < CH_TOT; i += (PK_BLOCKS - 1) * 256) {
        if (i < CH_W) {
            int row = i / 192, cc = i - row * 192;
            int m = row >> 11, j = row & 2047;
            int srow = (j & 3) * HID + (j >> 2);   // gate-interleave
            int c = cc * 8;
            const float* src = (c < INSZ) ? (Wih + ((size_t)m * G4H + srow) * INSZ + c)
                                          : (Whh + ((size_t)m * G4H + srow) * HID + (c - INSZ));
            store_bf8(Wb + (size_t)row * KIN + c,
                      *(const float4*)src, *(const float4*)(src + 4));
        } else if (i < CH_W + CH_L) {
            int i2 = i - CH_W;
            int row = i2 >> 6, cc = i2 & 63;
            const float* src = W_lin + (size_t)row * HID + cc * 8;
            store_bf8(Wlin + (size_t)row * HID + cc * 8,
                      *(const float4*)src, *(const float4*)(src + 4));
        } else {
            int i3 = i - (CH_W + CH_L);
            int row = i3 / 192, cc = i3 - row * 192;
            int c = cc * 8;
            u16* dst = A_tok + (size_t)row * KIN + c;
            if (row == NTOK) {
                *reinterpret_cast<int4*>(dst) = make_int4(0, 0, 0, 0);
            } else {
                const float* src = (c < INSZ) ? (x + (size_t)row * INSZ + c)
                                              : (h + (size_t)row * HID + (c - INSZ));
                store_bf8(dst, *(const float4*)src, *(const float4*)(src + 4));
            }
        }
    }
}

// ---------------------------------------------------------------------------
// Dispatch 1: fused GEMMs + LSTM epilogue.
//  gates ids [0,1408): 192x128 tile, K-FULL (1536), 4 waves of 96x64 (6x4
//    frags). Single-stage 40KB LDS, plain drain schedule (R0-proven at this
//    residency), 3 blocks/CU (launch_bounds(256,3)). 12.7 KB pulled/MFLOP
//    (vs 15.6 at 128^2) — pull-throughput is the measured limiter.
//    Wb gate-interleaved -> fused in-register LSTM epilogue (4x4 shfl_xor
//    transpose), unchanged math.
//  logodds ids [1408,1536): 64x128 tiles, K=512 (unchanged).
// LDS chunk-XOR swizzle unchanged (row&7 == l15&7 since 96,16 are mult. of 8).
// ---------------------------------------------------------------------------
__global__ __launch_bounds__(256, 3) void mega_gemm(
    const u16* __restrict__ A_tok,    // [4097][1536] token order bf16
    const u16* __restrict__ Wb,       // [4][2048][1536] gate-interleaved
    const u16* __restrict__ Wlin,     // [64][128][512]
    const float* __restrict__ et,     // [4096][512] f32
    const float* __restrict__ b_lin,  // [64,128]
    const float* __restrict__ c,      // [4096][512]
    const float* __restrict__ b_ih,   // [4,2048]
    const float* __restrict__ b_hh,   // [4,2048]
    const int* __restrict__ meta,
    const int* __restrict__ perm_ci,
    const int* __restrict__ perm_cat,
    float* __restrict__ out)
{
    // gates: As = S[0,12288) (192x64), Bs = S[12288,20480) (128x64)
    // log_odds reuses S[0,8192) for W staging and S[8192,12288) for et.
    __shared__ __align__(16) u16 S[20480];
    __shared__ int sperm[192];

    int tid = threadIdx.x;
    int lane = tid & 63, wave = tid >> 6;
    int qd = lane >> 4, l15 = lane & 15;
    int rsw = l15 & 7;

    int id = blockIdx.x;
    if (id < 1408) {
        // ---------------- gates GEMM, 192x128, K-full, drain loop ----------
        int g = id & 63;                      // (m,ct) group -> fixes XCD
        int rt = id >> 6;                     // 0..21 row tile
        int m = g >> 4, ct = g & 15;
        int pcnt = meta[m];
        if (rt * 192 >= pcnt) return;
        int row0 = meta[4 + m] + rt * 192;

        if (tid < 192) sperm[tid] = perm_ci[row0 + tid];
        __syncthreads();

        // per thread: 6 A chunks + 4 B chunks per K-step (q = j*256 + tid)
        const u16* gA[6]; const u16* gB[4];
        u16* lA[6]; u16* lB[4];
        #pragma unroll
        for (int j = 0; j < 6; ++j) {
            int q = j * 256 + tid;
            int row = q >> 3, kc = (q & 7) ^ (row & 7);
            int t = sperm[row];
            gA[j] = A_tok + (size_t)(t >= 0 ? t : NTOK) * KIN + kc * 8;
            lA[j] = &S[q * 8];
        }
        #pragma unroll
        for (int j = 0; j < 4; ++j) {
            int q = j * 256 + tid;
            int row = q >> 3, kc = (q & 7) ^ (row & 7);
            gB[j] = Wb + ((size_t)m * G4H + ct * 128 + row) * KIN + kc * 8;
            lB[j] = &S[12288 + q * 8];
        }

        int wm = wave >> 1, wn = wave & 1;    // wave tile: rows wm*96, cols wn*64

        f32x4 acc[6][4];
        #pragma unroll
        for (int i = 0; i < 6; ++i)
            #pragma unroll
            for (int j = 0; j < 4; ++j)
                acc[i][j] = (f32x4){0.f, 0.f, 0.f, 0.f};

        for (int ks = 0; ks < KIN / 64; ++ks) {
            #pragma unroll
            for (int j = 0; j < 6; ++j) { gl16(gA[j], lA[j]); gA[j] += 64; }
            #pragma unroll
            for (int j = 0; j < 4; ++j) { gl16(gB[j], lB[j]); gB[j] += 64; }
            __syncthreads();                  // compiler drains vmcnt here
            #pragma unroll
            for (int ks2 = 0; ks2 < 2; ++ks2) {
                int ch = (ks2 * 4 + qd) ^ rsw;
                bf16x8 fb[4];
                #pragma unroll
                for (int tj = 0; tj < 4; ++tj) {
                    int row = wn * 64 + tj * 16 + l15;
                    fb[tj] = *reinterpret_cast<const bf16x8*>(&S[12288 + row * 64 + ch * 8]);
                }
                #pragma unroll
                for (int ti = 0; ti < 6; ++ti) {
                    int row = wm * 96 + ti * 16 + l15;
                    bf16x8 fa = *reinterpret_cast<const bf16x8*>(&S[row * 64 + ch * 8]);
                    #pragma unroll
                    for (int tj = 0; tj < 4; ++tj)
                        acc[ti][tj] = __builtin_amdgcn_mfma_f32_16x16x32_bf16(fa, fb[tj], acc[ti][tj], 0, 0, 0);
                }
            }
            __syncthreads();
        }

        // -------- fused LSTM epilogue (R1-proven math; rows now 6x16) ------
        // packed col = ct*128 + wn*64 + tj*16 + l15 ; gate gt = l15&3,
        // unit u = ct*32 + wn*16 + tj*4 + (l15>>2). 4-lane group holds the 4
        // gates of one u over rows qd*4+rr; 4x4 shfl_xor transpose -> lane
        // (lane&3) ends with i,f,g,o of row rr = lane&3.
        int gt = l15 & 3;
        float bias[4];
        #pragma unroll
        for (int tj = 0; tj < 4; ++tj) {
            int u = ct * 32 + wn * 16 + tj * 4 + (l15 >> 2);
            bias[tj] = b_ih[m * G4H + gt * HID + u] + b_hh[m * G4H + gt * HID + u];
        }
        int b0 = lane & 1, b1 = lane & 2;
        const size_t o_h2 = (size_t)NTOK * CCH;
        const size_t o_c2 = o_h2 + (size_t)NTOK * HID;
        #pragma unroll
        for (int ti = 0; ti < 6; ++ti) {
            int t = sperm[wm * 96 + ti * 16 + qd * 4 + (lane & 3)];
            #pragma unroll
            for (int tj = 0; tj < 4; ++tj) {
                float v0 = acc[ti][tj][0] + bias[tj];
                float v1 = acc[ti][tj][1] + bias[tj];
                float v2 = acc[ti][tj][2] + bias[tj];
                float v3 = acc[ti][tj][3] + bias[tj];
                float tmp;
                tmp = __shfl_xor(b0 ? v0 : v1, 1); if (b0) v0 = tmp; else v1 = tmp;
                tmp = __shfl_xor(b0 ? v2 : v3, 1); if (b0) v2 = tmp; else v3 = tmp;
                tmp = __shfl_xor(b1 ? v0 : v2, 2); if (b1) v0 = tmp; else v2 = tmp;
                tmp = __shfl_xor(b1 ? v1 : v3, 2); if (b1) v1 = tmp; else v3 = tmp;
                if (t >= 0) {
                    int u = ct * 32 + wn * 16 + tj * 4 + (l15 >> 2);
                    float si = 1.f / (1.f + __expf(-v0));
                    float sf = 1.f / (1.f + __expf(-v1));
                    float tg = tanhf(v2);
                    float so = 1.f / (1.f + __expf(-v3));
                    float cold = c[(size_t)t * HID + u];
                    float c2 = sf * cold + si * tg;
                    float h2 = so * tanhf(c2);
                    out[o_h2 + (size_t)t * HID + u] = h2;
                    out[o_c2 + (size_t)t * HID + u] = c2;
                }
            }
        }
    } else {
        // ---------------- log_odds GEMM (64 x 128, K=512) ----------------
        u16* As = S;                          // 8192 u16
        u16* Bs = S + 8192;                   // 4096 u16
        int rtl = id - 1408;                  // 0..127 global slot tile
        int k = meta[136 + rtl];
        if (k < 0) return;
        int r0 = rtl * 64;

        if (tid < 64) sperm[tid] = perm_cat[r0 + tid];
        __syncthreads();

        int rb = tid >> 3;                    // 0..31
        int kc = (tid & 7) ^ (rb & 7);

        // B = Wlin[k] (128 x 64/iter) via gl16 into As
        const u16* gW[4]; u16* lW[4];
        #pragma unroll
        for (int i = 0; i < 4; ++i) {
            gW[i] = Wlin + ((size_t)k * CCH + i * 32 + rb) * HID + kc * 8;
            lW[i] = As + (i * 256 + wave * 64) * 8;
        }
        // A = et rows gathered, f32->bf16 VALU staging into Bs (64 x 64/iter)
        int ar = tid >> 2;                    // 0..63
        int acp = tid & 3;                    // 2 chunks each
        int at = sperm[ar];
        const float* asrc = (at >= 0) ? (et + (size_t)at * HID) : nullptr;

        f32x4 acc[4][2];
        #pragma unroll
        for (int i = 0; i < 4; ++i) {
            acc[i][0] = (f32x4){0.f, 0.f, 0.f, 0.f};
            acc[i][1] = (f32x4){0.f, 0.f, 0.f, 0.f};
        }

        for (int kk = 0; kk < HID; kk += 64) {
            #pragma unroll
            for (int i = 0; i < 4; ++i) { gl16(gW[i], lW[i]); gW[i] += 64; }
            #pragma unroll
            for (int j = 0; j < 2; ++j) {
                int dch = acp * 2 + j;
                int sch = dch ^ (ar & 7);
                u16* dst = &Bs[ar * 64 + dch * 8];
                if (asrc) {
                    const float* s = asrc + kk + sch * 8;
                    store_bf8(dst, *(const float4*)s, *(const float4*)(s + 4));
                } else {
                    *reinterpret_cast<int4*>(dst) = make_int4(0, 0, 0, 0);
                }
            }
            __syncthreads();
            #pragma unroll
            for (int ks2 = 0; ks2 < 2; ++ks2) {
                int ch = (ks2 * 4 + qd) ^ rsw;
                bf16x8 fa[4], fb[2];
                #pragma unroll
                for (int ti = 0; ti < 4; ++ti)
                    fa[ti] = *reinterpret_cast<const bf16x8*>(&Bs[(ti * 16 + l15) * 64 + ch * 8]);
                #pragma unroll
                for (int tj = 0; tj < 2; ++tj)
                    fb[tj] = *reinterpret_cast<const bf16x8*>(&As[(wave * 32 + tj * 16 + l15) * 64 + ch * 8]);
                #pragma unroll
                for (int ti = 0; ti < 4; ++ti)
                    #pragma unroll
                    for (int tj = 0; tj < 2; ++tj)
                        acc[ti][tj] = __builtin_amdgcn_mfma_f32_16x16x32_bf16(fa[ti], fb[tj], acc[ti][tj], 0, 0, 0);
            }
            __syncthreads();
        }

        #pragma unroll
        for (int ti = 0; ti < 4; ++ti) {
            #pragma unroll
            for (int tj = 0; tj < 2; ++tj) {
                int n = wave * 32 + tj * 16 + l15;
                float bias = b_lin[k * CCH + n];
                #pragma unroll
                for (int rr = 0; rr < 4; ++rr) {
                    int row = ti * 16 + qd * 4 + rr;
                    int t = sperm[row];
                    if (t >= 0)
                        out[(size_t)t * CCH + n] = acc[ti][tj][rr] + bias;
                }
            }
        }
    }
}

// ---------------------------------------------------------------------------
extern "C" void kernel_launch(void* const* d_in, const int* in_sizes, int n_in,
                              void* d_out, int out_size, void* d_ws, size_t ws_size,
                              hipStream_t stream) {
    const float* et    = (const float*)d_in[0];
    const float* x     = (const float*)d_in[1];
    const float* h     = (const float*)d_in[2];
    const float* c     = (const float*)d_in[3];
    const int*   cat   = (const int*)d_in[4];
    const int*   ci    = (const int*)d_in[5];
    const float* W_lin = (const float*)d_in[6];
    const float* b_lin = (const float*)d_in[7];
    const float* W_ih  = (const float*)d_in[8];
    const float* W_hh  = (const float*)d_in[9];
    const float* b_ih  = (const float*)d_in[10];
    const float* b_hh  = (const float*)d_in[11];
    float* out = (float*)d_out;

    char* ws = (char*)d_ws;
    int* meta     = (int*)ws;                         // 264 ints used (2 KB resv)
    int* perm_ci  = (int*)(ws + 2048);                // 4992 ints (20 KB resv)
    int* perm_cat = (int*)(ws + 22528);               // 8192 ints -> 55296
    u16* A_tok    = (u16*)(ws + 55296);               // 4097*1536*2 -> 12641280
    u16* Wb       = (u16*)(ws + 12641280);            // 8192*1536*2 -> 37807104
    u16* Wlin     = (u16*)(ws + 37807104);            // 8192*512*2  -> 46195712

    fat_pack<<<PK_BLOCKS, 256, 0, stream>>>(x, h, W_ih, W_hh, W_lin, ci, cat,
                                            meta, perm_ci, perm_cat, A_tok, Wb, Wlin);

    mega_gemm<<<1408 + 128, 256, 0, stream>>>(A_tok, Wb, Wlin, et, b_lin, c,
                                              b_ih, b_hh, meta, perm_ci, perm_cat, out);
}